// Round 2
// baseline (842.552 us; speedup 1.0000x reference)
//
#include <hip/hip_runtime.h>
#include <math.h>

#define LN_EPS 1e-5f
#define EPS_ATTN 1e-8f
#define SCALE 0.125f  // D^-0.5, D=64
#define CHUNKS 16

// ---------------------------------------------------------------------------
__device__ __forceinline__ float wsum64(float v) {
#pragma unroll
  for (int m = 1; m <= 32; m <<= 1) v += __shfl_xor(v, m, 64);
  return v;
}

// 16-lane allreduce sum on the VALU pipe via DPP (no LDS-pipe traffic).
__device__ __forceinline__ float red16(float v) {
  v += __int_as_float(__builtin_amdgcn_update_dpp(0, __float_as_int(v), 0xB1, 0xF, 0xF, true));
  v += __int_as_float(__builtin_amdgcn_update_dpp(0, __float_as_int(v), 0x4E, 0xF, 0xF, true));
  v += __int_as_float(__builtin_amdgcn_update_dpp(0, __float_as_int(v), 0x124, 0xF, 0xF, true));
  v += __int_as_float(__builtin_amdgcn_update_dpp(0, __float_as_int(v), 0x128, 0xF, 0xF, true));
  return v;
}

// ---------------------------------------------------------------------------
// Wave-local slot->qk: one wave, lane=d (uses precomputed M/cvec/uvec/s0).
__device__ void slot_qk_wave(int bi, float o, int lane,
    const float* __restrict__ M, const float* __restrict__ cvec,
    const float* __restrict__ uvec, const float* __restrict__ s0v,
    const float* __restrict__ g_sl, const float* __restrict__ beta_sl,
    float* qk, float* qb)
{
  float s  = wsum64(o);
  float s2 = wsum64(o * o);
  float mean = s * (1.0f / 64.0f);
  float var  = s2 * (1.0f / 64.0f) - mean * mean;
  float rstd = rsqrtf(var + LN_EPS);
  float ln = (o - mean) * rstd * g_sl[lane] + beta_sl[lane];

  float qv = cvec[lane];
#pragma unroll
  for (int t = 0; t < 64; ++t) qv += __shfl(ln, t, 64) * M[t * 64 + lane];
  qk[bi * 64 + lane] = qv;
  float pb = wsum64(ln * uvec[lane]);
  if (lane == 0) qb[bi] = s0v[0] + pb;
}

// ---------------------------------------------------------------------------
// Wave-local full slot update: one wave, lane=d. acc/asum are read with
// agent-scope RELAXED atomic loads: the producers' atomicAdds execute at the
// memory-side coherent point, so a coherent per-load read is both necessary
// (stale L1/L2 bypass) and sufficient (no fences / cache maintenance).
__device__ void slot_update_wave(int bi, int lane, int do_next,
    const float* S_in, float* S_out,
    float* acc, float* asum,
    const float* __restrict__ wv, const float* __restrict__ bv,
    const float* __restrict__ w_ih, const float* __restrict__ b_ih,
    const float* __restrict__ w_hh, const float* __restrict__ b_hh,
    const float* __restrict__ w1, const float* __restrict__ b1,
    const float* __restrict__ w2, const float* __restrict__ b2,
    const float* __restrict__ g_ff, const float* __restrict__ beta_ff,
    const float* __restrict__ M, const float* __restrict__ cvec,
    const float* __restrict__ uvec, const float* __restrict__ s0v,
    const float* __restrict__ g_sl, const float* __restrict__ beta_sl,
    float* qk, float* qb)
{
  float asv = __hip_atomic_load(&asum[bi], __ATOMIC_RELAXED,
                                __HIP_MEMORY_SCOPE_AGENT);
  float av  = __hip_atomic_load(&acc[bi * 64 + lane], __ATOMIC_RELAXED,
                                __HIP_MEMORY_SCOPE_AGENT);
  float v   = av / asv;
  if (do_next) {
    acc[bi * 64 + lane] = 0.0f;   // consumed by NEXT dispatch (L2 flushed at end)
    if (lane == 0) asum[bi] = 0.0f;
  }
  float sp = S_in[bi * 64 + lane];

  float upd = bv[lane];
#pragma unroll
  for (int e = 0; e < 64; ++e) upd += __shfl(v, e, 64) * wv[e * 64 + lane];

  float gxr = b_ih[lane], gxz = b_ih[64 + lane], gxn = b_ih[128 + lane];
  float ghr = b_hh[lane], ghz = b_hh[64 + lane], ghn = b_hh[128 + lane];
#pragma unroll 8
  for (int e = 0; e < 64; ++e) {
    float uu = __shfl(upd, e, 64), hh = __shfl(sp, e, 64);
    const float* wi = w_ih + e * 192;
    const float* wh = w_hh + e * 192;
    gxr += uu * wi[lane]; gxz += uu * wi[64 + lane]; gxn += uu * wi[128 + lane];
    ghr += hh * wh[lane]; ghz += hh * wh[64 + lane]; ghn += hh * wh[128 + lane];
  }
  float r  = 1.0f / (1.0f + __expf(-(gxr + ghr)));
  float z  = 1.0f / (1.0f + __expf(-(gxz + ghz)));
  float nw = tanhf(gxn + r * ghn);
  float sn = (1.0f - z) * nw + z * sp;

  float s  = wsum64(sn);
  float s2 = wsum64(sn * sn);
  float mean = s * (1.0f / 64.0f);
  float var  = s2 * (1.0f / 64.0f) - mean * mean;
  float rstd = rsqrtf(var + LN_EPS);
  float ff = (sn - mean) * rstd * g_ff[lane] + beta_ff[lane];

  float h1 = b1[lane], h2 = b1[64 + lane];
#pragma unroll
  for (int e = 0; e < 64; ++e) {
    float f = __shfl(ff, e, 64);
    h1 += f * w1[e * 128 + lane];
    h2 += f * w1[e * 128 + 64 + lane];
  }
  h1 = fmaxf(h1, 0.0f);
  h2 = fmaxf(h2, 0.0f);

  float o = sn + b2[lane];
#pragma unroll
  for (int t = 0; t < 64; ++t) o += __shfl(h1, t, 64) * w2[t * 64 + lane];
#pragma unroll
  for (int t = 0; t < 64; ++t) o += __shfl(h2, t, 64) * w2[(64 + t) * 64 + lane];

  S_out[bi * 64 + lane] = o;

  if (do_next)
    slot_qk_wave(bi, o, lane, M, cvec, uvec, s0v, g_sl, beta_sl, qk, qb);
}

// ---------------------------------------------------------------------------
// Init + prep fused + zero per-batch arrival counters. grid = 577 x 64.
__global__ __launch_bounds__(64) void k_init(
    const float* __restrict__ noise, const float* __restrict__ mu,
    const float* __restrict__ lsig,
    const float* __restrict__ wq, const float* __restrict__ bq,
    const float* __restrict__ wk, const float* __restrict__ bk,
    const float* __restrict__ g_sl, const float* __restrict__ beta_sl,
    float* __restrict__ S_buf, float* __restrict__ qk, float* __restrict__ qb,
    float* __restrict__ acc, float* __restrict__ asum,
    float* __restrict__ M, float* __restrict__ cvec,
    float* __restrict__ uvec, float* __restrict__ s0v,
    int* __restrict__ cnt)
{
  int bi = blockIdx.x;
  int lane = threadIdx.x;
  if (bi < 512) {
    float sl = mu[lane] + __expf(lsig[lane]) * noise[bi * 64 + lane];
    S_buf[bi * 64 + lane] = sl;
    acc[bi * 64 + lane] = 0.0f;
    if (lane == 0) asum[bi] = 0.0f;
    if (lane == 0 && (bi & 7) == 0) cnt[bi >> 3] = 0;  // one per batch

    float s  = wsum64(sl);
    float s2 = wsum64(sl * sl);
    float mean = s * (1.0f / 64.0f);
    float var  = s2 * (1.0f / 64.0f) - mean * mean;
    float rstd = rsqrtf(var + LN_EPS);
    float ln = (sl - mean) * rstd * g_sl[lane] + beta_sl[lane];

    float q = bq[lane];
#pragma unroll
    for (int t = 0; t < 64; ++t) q += __shfl(ln, t, 64) * wq[t * 64 + lane];
    float qkl = 0.0f;
#pragma unroll
    for (int d = 0; d < 64; ++d) qkl += __shfl(q, d, 64) * wk[lane * 64 + d];
    qk[bi * 64 + lane] = qkl * SCALE;
    float qbl = wsum64(q * bk[lane]);
    if (lane == 0) qb[bi] = qbl * SCALE;
  } else if (bi < 576) {
    int t = bi - 512;
    float wqv = wq[t * 64 + lane];
    float m = 0.0f;
#pragma unroll
    for (int d = 0; d < 64; ++d) m += __shfl(wqv, d, 64) * wk[lane * 64 + d];
    M[t * 64 + lane] = m * SCALE;
    float uv = wsum64(wqv * bk[lane]);
    if (lane == 0) uvec[t] = uv * SCALE;
  } else {
    float bqv = bq[lane];
    float cc = 0.0f;
#pragma unroll
    for (int j = 0; j < 64; ++j) cc += __shfl(bqv, j, 64) * wk[lane * 64 + j];
    cvec[lane] = cc * SCALE;
    float ss = wsum64(bq[lane] * bk[lane]);
    if (lane == 0) s0v[0] = ss * SCALE;
  }
}

// ---------------------------------------------------------------------------
// Fused step: streaming pass + per-batch tail slot-update.
// grid = (CHUNKS, 64), block = 256.
// Arrival counter is a RELAXED agent-scope RMW (no cache maintenance — the
// acc/asum atomics are already globally visible once vmcnt drains at the
// __syncthreads before it). Only the TRUE last arriver (old == 15) updates:
// its 4 waves each process 2 slots. Everyone else exits; no spinning.
__global__ __launch_bounds__(256) void k_step(
    const float* __restrict__ inputs,
    const float* __restrict__ g_in, const float* __restrict__ beta_in,
    float* qk, float* qb,                 // read (this iter) + written (next iter)
    float* acc, float* asum,
    const float* S_in, float* S_out,
    const float* __restrict__ wv, const float* __restrict__ bv,
    const float* __restrict__ w_ih, const float* __restrict__ b_ih,
    const float* __restrict__ w_hh, const float* __restrict__ b_hh,
    const float* __restrict__ w1, const float* __restrict__ b1,
    const float* __restrict__ w2, const float* __restrict__ b2,
    const float* __restrict__ g_ff, const float* __restrict__ beta_ff,
    const float* __restrict__ M, const float* __restrict__ cvec,
    const float* __restrict__ uvec, const float* __restrict__ s0v,
    const float* __restrict__ g_sl, const float* __restrict__ beta_sl,
    int* cnt, int do_next)
{
  __shared__ float lds_acc[4][512];
  __shared__ float lds_as[4][8];
  __shared__ int s_old;
  const int b = blockIdx.y;
  const int chunk = blockIdx.x;
  const int tid = threadIdx.x;
  const int lane = tid & 63;
  const int wave = tid >> 6;
  const int p = lane & 15;

  float4 g4  = ((const float4*)g_in)[p];
  float4 be4 = ((const float4*)beta_in)[p];
  float4 qkv[8];
  float qbv[8];
  const float4* qk4 = (const float4*)(qk + b * 512);
#pragma unroll
  for (int i = 0; i < 8; ++i) {
    qkv[i] = qk4[i * 16 + p];
    qbv[i] = qb[b * 8 + i];
  }

  float4 accl[8];
  float asl[8];
#pragma unroll
  for (int i = 0; i < 8; ++i) { accl[i] = make_float4(0.f, 0.f, 0.f, 0.f); asl[i] = 0.f; }

  const float4* in4 = (const float4*)(inputs + (size_t)b * 4096 * 64);
  const int rb0 = chunk * 256 + wave * 8;  // this wave's iter-0 base row

  float4 xa = in4[rb0 * 16 + lane];
  float4 xb = in4[(rb0 + 4) * 16 + lane];
  for (int it = 0; it < 8; ++it) {
    float4 na, nb;
    if (it < 7) {
      na = in4[(rb0 + (it + 1) * 32) * 16 + lane];
      nb = in4[(rb0 + (it + 1) * 32 + 4) * 16 + lane];
    }

    // ---- group A ----
    {
      float s  = red16(xa.x + xa.y + xa.z + xa.w);
      float s2 = red16(xa.x * xa.x + xa.y * xa.y + xa.z * xa.z + xa.w * xa.w);
      float mean = s * 0.015625f;
      float var  = s2 * 0.015625f - mean * mean;
      float rstd = rsqrtf(var + LN_EPS);
      float4 xln;
      xln.x = (xa.x - mean) * rstd * g4.x + be4.x;
      xln.y = (xa.y - mean) * rstd * g4.y + be4.y;
      xln.z = (xa.z - mean) * rstd * g4.z + be4.z;
      xln.w = (xa.w - mean) * rstd * g4.w + be4.w;
      float dots[8];
#pragma unroll
      for (int i = 0; i < 8; ++i) {
        float d = xln.x * qkv[i].x + xln.y * qkv[i].y + xln.z * qkv[i].z + xln.w * qkv[i].w;
        dots[i] = red16(d) + qbv[i];
      }
      float pv[8];
      float ps = 0.0f;
#pragma unroll
      for (int i = 0; i < 8; ++i) { pv[i] = __expf(dots[i]); ps += pv[i]; }
      float inv = __builtin_amdgcn_rcpf(ps);
#pragma unroll
      for (int i = 0; i < 8; ++i) {
        float pp = pv[i] * inv + EPS_ATTN;
        asl[i] += pp;
        accl[i].x += pp * xln.x;
        accl[i].y += pp * xln.y;
        accl[i].z += pp * xln.z;
        accl[i].w += pp * xln.w;
      }
    }
    // ---- group B ----
    {
      float s  = red16(xb.x + xb.y + xb.z + xb.w);
      float s2 = red16(xb.x * xb.x + xb.y * xb.y + xb.z * xb.z + xb.w * xb.w);
      float mean = s * 0.015625f;
      float var  = s2 * 0.015625f - mean * mean;
      float rstd = rsqrtf(var + LN_EPS);
      float4 xln;
      xln.x = (xb.x - mean) * rstd * g4.x + be4.x;
      xln.y = (xb.y - mean) * rstd * g4.y + be4.y;
      xln.z = (xb.z - mean) * rstd * g4.z + be4.z;
      xln.w = (xb.w - mean) * rstd * g4.w + be4.w;
      float dots[8];
#pragma unroll
      for (int i = 0; i < 8; ++i) {
        float d = xln.x * qkv[i].x + xln.y * qkv[i].y + xln.z * qkv[i].z + xln.w * qkv[i].w;
        dots[i] = red16(d) + qbv[i];
      }
      float pv[8];
      float ps = 0.0f;
#pragma unroll
      for (int i = 0; i < 8; ++i) { pv[i] = __expf(dots[i]); ps += pv[i]; }
      float inv = __builtin_amdgcn_rcpf(ps);
#pragma unroll
      for (int i = 0; i < 8; ++i) {
        float pp = pv[i] * inv + EPS_ATTN;
        asl[i] += pp;
        accl[i].x += pp * xln.x;
        accl[i].y += pp * xln.y;
        accl[i].z += pp * xln.z;
        accl[i].w += pp * xln.w;
      }
    }
    xa = na;
    xb = nb;
  }

#pragma unroll
  for (int i = 0; i < 8; ++i) {
#pragma unroll
    for (int m = 16; m <= 32; m <<= 1) {
      accl[i].x += __shfl_xor(accl[i].x, m, 64);
      accl[i].y += __shfl_xor(accl[i].y, m, 64);
      accl[i].z += __shfl_xor(accl[i].z, m, 64);
      accl[i].w += __shfl_xor(accl[i].w, m, 64);
      asl[i]    += __shfl_xor(asl[i], m, 64);
    }
  }

  if (lane < 16) {
    float4* dst = (float4*)lds_acc[wave];
#pragma unroll
    for (int i = 0; i < 8; ++i) dst[i * 16 + p] = accl[i];
  }
  if (lane == 0) {
#pragma unroll
    for (int i = 0; i < 8; ++i) lds_as[wave][i] = asl[i];
  }
  __syncthreads();

  for (int f = tid; f < 512; f += 256) {
    float ssum = lds_acc[0][f] + lds_acc[1][f] + lds_acc[2][f] + lds_acc[3][f];
    atomicAdd(&acc[b * 512 + f], ssum);
  }
  if (tid < 8) {
    float ssum = lds_as[0][tid] + lds_as[1][tid] + lds_as[2][tid] + lds_as[3][tid];
    atomicAdd(&asum[b * 8 + tid], ssum);
  }

  // ---- fused per-batch tail ----
  // __syncthreads drains vmcnt(0): this block's device-scope atomicAdds are
  // committed at the coherent point before the RELAXED counter RMW below.
  __syncthreads();
  if (tid == 0)
    s_old = __hip_atomic_fetch_add(&cnt[b], 1, __ATOMIC_RELAXED,
                                   __HIP_MEMORY_SCOPE_AGENT);
  __syncthreads();
  if (s_old != 15) return;             // only the TRUE last arriver updates
  if (tid == 0) cnt[b] = 0;            // reset for next k_step

#pragma unroll 1
  for (int kk = 0; kk < 2; ++kk) {
    slot_update_wave(b * 8 + wave * 2 + kk, lane, do_next, S_in, S_out,
                     acc, asum, wv, bv, w_ih, b_ih, w_hh, b_hh,
                     w1, b1, w2, b2, g_ff, beta_ff,
                     M, cvec, uvec, s0v, g_sl, beta_sl, qk, qb);
  }
}

// ---------------------------------------------------------------------------
extern "C" void kernel_launch(void* const* d_in, const int* in_sizes, int n_in,
                              void* d_out, int out_size, void* d_ws, size_t ws_size,
                              hipStream_t stream) {
  const float* inputs  = (const float*)d_in[0];
  const float* noise   = (const float*)d_in[1];
  const float* mu      = (const float*)d_in[2];
  const float* lsig    = (const float*)d_in[3];
  const float* wq      = (const float*)d_in[4];
  const float* bq      = (const float*)d_in[5];
  const float* wk      = (const float*)d_in[6];
  const float* bk      = (const float*)d_in[7];
  const float* wv      = (const float*)d_in[8];
  const float* bv      = (const float*)d_in[9];
  const float* w_ih    = (const float*)d_in[10];
  const float* b_ih    = (const float*)d_in[11];
  const float* w_hh    = (const float*)d_in[12];
  const float* b_hh    = (const float*)d_in[13];
  const float* w1      = (const float*)d_in[14];
  const float* b1      = (const float*)d_in[15];
  const float* w2      = (const float*)d_in[16];
  const float* b2      = (const float*)d_in[17];
  const float* g_in    = (const float*)d_in[18];
  const float* beta_in = (const float*)d_in[19];
  const float* g_sl    = (const float*)d_in[20];
  const float* beta_sl = (const float*)d_in[21];
  const float* g_ff    = (const float*)d_in[22];
  const float* beta_ff = (const float*)d_in[23];

  float* S_buf = (float*)d_ws;        // [64*8*64]
  float* qk    = S_buf + 32768;       // [64*8*64]
  float* qb    = qk + 32768;          // [64*8]
  float* acc   = qb + 512;            // [64*8*64]
  float* asum  = acc + 32768;         // [64*8]
  float* M     = asum + 512;          // [64*64]
  float* cvec  = M + 4096;            // [64]
  float* uvec  = cvec + 64;           // [64]
  float* s0v   = uvec + 64;           // [1]
  int*   cnt   = (int*)(s0v + 1);     // [64] per-batch arrival counters
  float* out   = (float*)d_out;

  k_init<<<577, 64, 0, stream>>>(noise, mu, lsig, wq, bq, wk, bk,
                                 g_sl, beta_sl, S_buf, qk, qb, acc, asum,
                                 M, cvec, uvec, s0v, cnt);

  for (int t = 0; t < 3; ++t) {
    float* dst = (t == 2) ? out : S_buf;
    k_step<<<dim3(CHUNKS, 64), 256, 0, stream>>>(
        inputs, g_in, beta_in, qk, qb, acc, asum,
        S_buf, dst, wv, bv, w_ih, b_ih, w_hh, b_hh, w1, b1, w2, b2,
        g_ff, beta_ff, M, cvec, uvec, s0v, g_sl, beta_sl,
        cnt, (t == 2) ? 0 : 1);
  }
}

// Round 3
// 294.981 us; speedup vs baseline: 2.8563x; 2.8563x over previous
//
#include <hip/hip_runtime.h>
#include <math.h>

#define LN_EPS 1e-5f
#define EPS_ATTN 1e-8f
#define SCALE 0.125f  // D^-0.5, D=64
#define CHUNKS 32

// ---------------------------------------------------------------------------
__device__ __forceinline__ float wsum64(float v) {
#pragma unroll
  for (int m = 1; m <= 32; m <<= 1) v += __shfl_xor(v, m, 64);
  return v;
}

// 16-lane allreduce sum on the VALU pipe via DPP (no LDS-pipe traffic).
__device__ __forceinline__ float red16(float v) {
  v += __int_as_float(__builtin_amdgcn_update_dpp(0, __float_as_int(v), 0xB1, 0xF, 0xF, true));
  v += __int_as_float(__builtin_amdgcn_update_dpp(0, __float_as_int(v), 0x4E, 0xF, 0xF, true));
  v += __int_as_float(__builtin_amdgcn_update_dpp(0, __float_as_int(v), 0x124, 0xF, 0xF, true));
  v += __int_as_float(__builtin_amdgcn_update_dpp(0, __float_as_int(v), 0x128, 0xF, 0xF, true));
  return v;
}

// ---------------------------------------------------------------------------
// Wave-local slot->qk: one wave, lane=d (uses precomputed M/cvec/uvec/s0).
__device__ void slot_qk_wave(int bi, float o, int lane,
    const float* __restrict__ M, const float* __restrict__ cvec,
    const float* __restrict__ uvec, const float* __restrict__ s0v,
    const float* __restrict__ g_sl, const float* __restrict__ beta_sl,
    float* __restrict__ qk, float* __restrict__ qb)
{
  float s  = wsum64(o);
  float s2 = wsum64(o * o);
  float mean = s * (1.0f / 64.0f);
  float var  = s2 * (1.0f / 64.0f) - mean * mean;
  float rstd = rsqrtf(var + LN_EPS);
  float ln = (o - mean) * rstd * g_sl[lane] + beta_sl[lane];

  float qv = cvec[lane];
#pragma unroll
  for (int t = 0; t < 64; ++t) qv += __shfl(ln, t, 64) * M[t * 64 + lane];
  qk[bi * 64 + lane] = qv;
  float pb = wsum64(ln * uvec[lane]);
  if (lane == 0) qb[bi] = s0v[0] + pb;
}

// ---------------------------------------------------------------------------
// Wave-local full slot update: one wave, lane=d. Zero barriers on the chain.
// Plain loads of acc/asum are safe: producer k_main is a PRIOR dispatch
// (dispatch boundary flushes/invalidates caches).
__device__ void slot_update_wave(int bi, int lane, int do_next,
    const float* __restrict__ S_in, float* __restrict__ S_out,
    float* __restrict__ acc, float* __restrict__ asum,
    const float* __restrict__ wv, const float* __restrict__ bv,
    const float* __restrict__ w_ih, const float* __restrict__ b_ih,
    const float* __restrict__ w_hh, const float* __restrict__ b_hh,
    const float* __restrict__ w1, const float* __restrict__ b1,
    const float* __restrict__ w2, const float* __restrict__ b2,
    const float* __restrict__ g_ff, const float* __restrict__ beta_ff,
    const float* __restrict__ M, const float* __restrict__ cvec,
    const float* __restrict__ uvec, const float* __restrict__ s0v,
    const float* __restrict__ g_sl, const float* __restrict__ beta_sl,
    float* __restrict__ qk, float* __restrict__ qb)
{
  float asv = asum[bi];
  float av  = acc[bi * 64 + lane];
  float v   = av / asv;
  if (do_next) {
    acc[bi * 64 + lane] = 0.0f;
    if (lane == 0) asum[bi] = 0.0f;
  }
  float sp = S_in[bi * 64 + lane];

  float upd = bv[lane];
#pragma unroll
  for (int e = 0; e < 64; ++e) upd += __shfl(v, e, 64) * wv[e * 64 + lane];

  float gxr = b_ih[lane], gxz = b_ih[64 + lane], gxn = b_ih[128 + lane];
  float ghr = b_hh[lane], ghz = b_hh[64 + lane], ghn = b_hh[128 + lane];
#pragma unroll 16
  for (int e = 0; e < 64; ++e) {
    float uu = __shfl(upd, e, 64), hh = __shfl(sp, e, 64);
    const float* wi = w_ih + e * 192;
    const float* wh = w_hh + e * 192;
    gxr += uu * wi[lane]; gxz += uu * wi[64 + lane]; gxn += uu * wi[128 + lane];
    ghr += hh * wh[lane]; ghz += hh * wh[64 + lane]; ghn += hh * wh[128 + lane];
  }
  float r  = 1.0f / (1.0f + __expf(-(gxr + ghr)));
  float z  = 1.0f / (1.0f + __expf(-(gxz + ghz)));
  float nw = tanhf(gxn + r * ghn);
  float sn = (1.0f - z) * nw + z * sp;

  float s  = wsum64(sn);
  float s2 = wsum64(sn * sn);
  float mean = s * (1.0f / 64.0f);
  float var  = s2 * (1.0f / 64.0f) - mean * mean;
  float rstd = rsqrtf(var + LN_EPS);
  float ff = (sn - mean) * rstd * g_ff[lane] + beta_ff[lane];

  float h1 = b1[lane], h2 = b1[64 + lane];
#pragma unroll
  for (int e = 0; e < 64; ++e) {
    float f = __shfl(ff, e, 64);
    h1 += f * w1[e * 128 + lane];
    h2 += f * w1[e * 128 + 64 + lane];
  }
  h1 = fmaxf(h1, 0.0f);
  h2 = fmaxf(h2, 0.0f);

  float o = sn + b2[lane];
#pragma unroll
  for (int t = 0; t < 64; ++t) o += __shfl(h1, t, 64) * w2[t * 64 + lane];
#pragma unroll
  for (int t = 0; t < 64; ++t) o += __shfl(h2, t, 64) * w2[(64 + t) * 64 + lane];

  S_out[bi * 64 + lane] = o;

  if (do_next)
    slot_qk_wave(bi, o, lane, M, cvec, uvec, s0v, g_sl, beta_sl, qk, qb);
}

// ---------------------------------------------------------------------------
// Init + prep fused (7 nodes total). grid = 577 blocks x 64 lanes.
__global__ __launch_bounds__(64) void k_init(
    const float* __restrict__ noise, const float* __restrict__ mu,
    const float* __restrict__ lsig,
    const float* __restrict__ wq, const float* __restrict__ bq,
    const float* __restrict__ wk, const float* __restrict__ bk,
    const float* __restrict__ g_sl, const float* __restrict__ beta_sl,
    float* __restrict__ S_buf, float* __restrict__ qk, float* __restrict__ qb,
    float* __restrict__ acc, float* __restrict__ asum,
    float* __restrict__ M, float* __restrict__ cvec,
    float* __restrict__ uvec, float* __restrict__ s0v)
{
  int bi = blockIdx.x;
  int lane = threadIdx.x;
  if (bi < 512) {
    float sl = mu[lane] + __expf(lsig[lane]) * noise[bi * 64 + lane];
    S_buf[bi * 64 + lane] = sl;
    acc[bi * 64 + lane] = 0.0f;
    if (lane == 0) asum[bi] = 0.0f;

    float s  = wsum64(sl);
    float s2 = wsum64(sl * sl);
    float mean = s * (1.0f / 64.0f);
    float var  = s2 * (1.0f / 64.0f) - mean * mean;
    float rstd = rsqrtf(var + LN_EPS);
    float ln = (sl - mean) * rstd * g_sl[lane] + beta_sl[lane];

    float q = bq[lane];
#pragma unroll
    for (int t = 0; t < 64; ++t) q += __shfl(ln, t, 64) * wq[t * 64 + lane];
    float qkl = 0.0f;
#pragma unroll
    for (int d = 0; d < 64; ++d) qkl += __shfl(q, d, 64) * wk[lane * 64 + d];
    qk[bi * 64 + lane] = qkl * SCALE;
    float qbl = wsum64(q * bk[lane]);
    if (lane == 0) qb[bi] = qbl * SCALE;
  } else if (bi < 576) {
    int t = bi - 512;
    float wqv = wq[t * 64 + lane];
    float m = 0.0f;
#pragma unroll
    for (int d = 0; d < 64; ++d) m += __shfl(wqv, d, 64) * wk[lane * 64 + d];
    M[t * 64 + lane] = m * SCALE;
    float uv = wsum64(wqv * bk[lane]);
    if (lane == 0) uvec[t] = uv * SCALE;
  } else {
    float bqv = bq[lane];
    float cc = 0.0f;
#pragma unroll
    for (int j = 0; j < 64; ++j) cc += __shfl(bqv, j, 64) * wk[lane * 64 + j];
    cvec[lane] = cc * SCALE;
    float ss = wsum64(bq[lane] * bk[lane]);
    if (lane == 0) s0v[0] = ss * SCALE;
  }
}

// ---------------------------------------------------------------------------
// Main streaming pass. grid = (CHUNKS=32, 64), block = 256.
// VGPR diet: qk fragments live in LDS (shared by all 4 waves; read once per
// iteration in an i-loop shared by row-groups A and B). __launch_bounds__
// (256,5) caps VGPR at 102 -> 5 waves/SIMD; grid 2048 blocks = 8 blocks/CU
// dispatched so the extra occupancy is used.
__global__ __launch_bounds__(256, 5) void k_main(
    const float* __restrict__ inputs,
    const float* __restrict__ g_in, const float* __restrict__ beta_in,
    const float* __restrict__ qk, const float* __restrict__ qb,
    float* __restrict__ acc, float* __restrict__ asum)
{
  __shared__ float lds_qk[512];
  __shared__ float lds_acc[4][512];
  __shared__ float lds_as[4][8];
  const int b = blockIdx.y;
  const int chunk = blockIdx.x;
  const int tid = threadIdx.x;
  const int lane = tid & 63;
  const int wave = tid >> 6;
  const int p = lane & 15;

  // stage per-batch qk into LDS (2 KB), shared by all waves
  if (tid < 128)
    ((float4*)lds_qk)[tid] = ((const float4*)(qk + b * 512))[tid];

  float4 g4  = ((const float4*)g_in)[p];
  float4 be4 = ((const float4*)beta_in)[p];
  float qbv[8];
#pragma unroll
  for (int i = 0; i < 8; ++i) qbv[i] = qb[b * 8 + i];

  float4 accl[8];
  float asl[8];
#pragma unroll
  for (int i = 0; i < 8; ++i) { accl[i] = make_float4(0.f, 0.f, 0.f, 0.f); asl[i] = 0.f; }

  __syncthreads();  // lds_qk ready

  const float4* in4 = (const float4*)(inputs + (size_t)b * 4096 * 64);
  const float4* qk4 = (const float4*)lds_qk;
  const int rb0 = chunk * 128 + wave * 8;  // this wave's iter-0 base row

  float4 xa = in4[rb0 * 16 + lane];
  float4 xb = in4[(rb0 + 4) * 16 + lane];
  for (int it = 0; it < 4; ++it) {
    float4 na, nb;
    if (it < 3) {
      na = in4[(rb0 + (it + 1) * 32) * 16 + lane];
      nb = in4[(rb0 + (it + 1) * 32 + 4) * 16 + lane];
    }

    // ---- LayerNorm, both groups ----
    float sA  = red16(xa.x + xa.y + xa.z + xa.w);
    float s2A = red16(xa.x * xa.x + xa.y * xa.y + xa.z * xa.z + xa.w * xa.w);
    float meanA = sA * 0.015625f;
    float varA  = s2A * 0.015625f - meanA * meanA;
    float rstdA = rsqrtf(varA + LN_EPS);
    float4 xlnA;
    xlnA.x = (xa.x - meanA) * rstdA * g4.x + be4.x;
    xlnA.y = (xa.y - meanA) * rstdA * g4.y + be4.y;
    xlnA.z = (xa.z - meanA) * rstdA * g4.z + be4.z;
    xlnA.w = (xa.w - meanA) * rstdA * g4.w + be4.w;

    float sB  = red16(xb.x + xb.y + xb.z + xb.w);
    float s2B = red16(xb.x * xb.x + xb.y * xb.y + xb.z * xb.z + xb.w * xb.w);
    float meanB = sB * 0.015625f;
    float varB  = s2B * 0.015625f - meanB * meanB;
    float rstdB = rsqrtf(varB + LN_EPS);
    float4 xlnB;
    xlnB.x = (xb.x - meanB) * rstdB * g4.x + be4.x;
    xlnB.y = (xb.y - meanB) * rstdB * g4.y + be4.y;
    xlnB.z = (xb.z - meanB) * rstdB * g4.z + be4.z;
    xlnB.w = (xb.w - meanB) * rstdB * g4.w + be4.w;

    // ---- dots + exp, qk read ONCE from LDS per slot for both groups ----
    float pvA[8], pvB[8];
    float psA = 0.0f, psB = 0.0f;
#pragma unroll
    for (int i = 0; i < 8; ++i) {
      float4 qv = qk4[i * 16 + p];
      float da = xlnA.x * qv.x + xlnA.y * qv.y + xlnA.z * qv.z + xlnA.w * qv.w;
      float db = xlnB.x * qv.x + xlnB.y * qv.y + xlnB.z * qv.z + xlnB.w * qv.w;
      da = red16(da) + qbv[i];
      db = red16(db) + qbv[i];
      float ea = __expf(da);   // no max-subtraction (|dots| << 88)
      float eb = __expf(db);
      pvA[i] = ea; psA += ea;
      pvB[i] = eb; psB += eb;
    }
    float invA = __builtin_amdgcn_rcpf(psA);
    float invB = __builtin_amdgcn_rcpf(psB);
#pragma unroll
    for (int i = 0; i < 8; ++i) {
      float ppa = pvA[i] * invA + EPS_ATTN;
      float ppb = pvB[i] * invB + EPS_ATTN;
      asl[i] += ppa + ppb;
      accl[i].x += ppa * xlnA.x; accl[i].x += ppb * xlnB.x;
      accl[i].y += ppa * xlnA.y; accl[i].y += ppb * xlnB.y;
      accl[i].z += ppa * xlnA.z; accl[i].z += ppb * xlnB.z;
      accl[i].w += ppa * xlnA.w; accl[i].w += ppb * xlnB.w;
    }
    xa = na;
    xb = nb;
  }

#pragma unroll
  for (int i = 0; i < 8; ++i) {
#pragma unroll
    for (int m = 16; m <= 32; m <<= 1) {
      accl[i].x += __shfl_xor(accl[i].x, m, 64);
      accl[i].y += __shfl_xor(accl[i].y, m, 64);
      accl[i].z += __shfl_xor(accl[i].z, m, 64);
      accl[i].w += __shfl_xor(accl[i].w, m, 64);
      asl[i]    += __shfl_xor(asl[i], m, 64);
    }
  }

  if (lane < 16) {
    float4* dst = (float4*)lds_acc[wave];
#pragma unroll
    for (int i = 0; i < 8; ++i) dst[i * 16 + p] = accl[i];
  }
  if (lane == 0) {
#pragma unroll
    for (int i = 0; i < 8; ++i) lds_as[wave][i] = asl[i];
  }
  __syncthreads();

  for (int f = tid; f < 512; f += 256) {
    float ssum = lds_acc[0][f] + lds_acc[1][f] + lds_acc[2][f] + lds_acc[3][f];
    atomicAdd(&acc[b * 512 + f], ssum);
  }
  if (tid < 8) {
    float ssum = lds_as[0][tid] + lds_as[1][tid] + lds_as[2][tid] + lds_as[3][tid];
    atomicAdd(&asum[b * 8 + tid], ssum);
  }
}

// ---------------------------------------------------------------------------
// Per-slot update: 512 blocks x 64 lanes, fully parallel wave-local chains.
__global__ __launch_bounds__(64) void k_update(
    const float* __restrict__ S_in, float* __restrict__ S_out,
    float* __restrict__ acc, float* __restrict__ asum,
    const float* __restrict__ wv, const float* __restrict__ bv,
    const float* __restrict__ w_ih, const float* __restrict__ b_ih,
    const float* __restrict__ w_hh, const float* __restrict__ b_hh,
    const float* __restrict__ w1, const float* __restrict__ b1,
    const float* __restrict__ w2, const float* __restrict__ b2,
    const float* __restrict__ g_ff, const float* __restrict__ beta_ff,
    const float* __restrict__ M, const float* __restrict__ cvec,
    const float* __restrict__ uvec, const float* __restrict__ s0v,
    const float* __restrict__ g_sl, const float* __restrict__ beta_sl,
    float* __restrict__ qk, float* __restrict__ qb, int do_next)
{
  slot_update_wave(blockIdx.x, threadIdx.x, do_next,
                   S_in, S_out, acc, asum, wv, bv, w_ih, b_ih, w_hh, b_hh,
                   w1, b1, w2, b2, g_ff, beta_ff, M, cvec, uvec, s0v,
                   g_sl, beta_sl, qk, qb);
}

// ---------------------------------------------------------------------------
extern "C" void kernel_launch(void* const* d_in, const int* in_sizes, int n_in,
                              void* d_out, int out_size, void* d_ws, size_t ws_size,
                              hipStream_t stream) {
  const float* inputs  = (const float*)d_in[0];
  const float* noise   = (const float*)d_in[1];
  const float* mu      = (const float*)d_in[2];
  const float* lsig    = (const float*)d_in[3];
  const float* wq      = (const float*)d_in[4];
  const float* bq      = (const float*)d_in[5];
  const float* wk      = (const float*)d_in[6];
  const float* bk      = (const float*)d_in[7];
  const float* wv      = (const float*)d_in[8];
  const float* bv      = (const float*)d_in[9];
  const float* w_ih    = (const float*)d_in[10];
  const float* b_ih    = (const float*)d_in[11];
  const float* w_hh    = (const float*)d_in[12];
  const float* b_hh    = (const float*)d_in[13];
  const float* w1      = (const float*)d_in[14];
  const float* b1      = (const float*)d_in[15];
  const float* w2      = (const float*)d_in[16];
  const float* b2      = (const float*)d_in[17];
  const float* g_in    = (const float*)d_in[18];
  const float* beta_in = (const float*)d_in[19];
  const float* g_sl    = (const float*)d_in[20];
  const float* beta_sl = (const float*)d_in[21];
  const float* g_ff    = (const float*)d_in[22];
  const float* beta_ff = (const float*)d_in[23];

  float* S_buf = (float*)d_ws;        // [64*8*64]
  float* qk    = S_buf + 32768;       // [64*8*64]
  float* qb    = qk + 32768;          // [64*8]
  float* acc   = qb + 512;            // [64*8*64]
  float* asum  = acc + 32768;         // [64*8]
  float* M     = asum + 512;          // [64*64]
  float* cvec  = M + 4096;            // [64]
  float* uvec  = cvec + 64;           // [64]
  float* s0v   = uvec + 64;           // [1]
  float* out   = (float*)d_out;

  k_init<<<577, 64, 0, stream>>>(noise, mu, lsig, wq, bq, wk, bk,
                                 g_sl, beta_sl, S_buf, qk, qb, acc, asum,
                                 M, cvec, uvec, s0v);

  for (int t = 0; t < 3; ++t) {
    k_main<<<dim3(CHUNKS, 64), 256, 0, stream>>>(inputs, g_in, beta_in,
                                                 qk, qb, acc, asum);
    float* dst = (t == 2) ? out : S_buf;
    k_update<<<512, 64, 0, stream>>>(S_buf, dst, acc, asum, wv, bv,
                                     w_ih, b_ih, w_hh, b_hh, w1, b1, w2, b2,
                                     g_ff, beta_ff, M, cvec, uvec, s0v,
                                     g_sl, beta_sl, qk, qb, (t == 2) ? 0 : 1);
  }
}

// Round 4
// 223.990 us; speedup vs baseline: 3.7616x; 1.3169x over previous
//
#include <hip/hip_runtime.h>
#include <math.h>

#define LN_EPS 1e-5f
#define EPS_ATTN 1e-8f
#define SCALE 0.125f  // D^-0.5, D=64
#define CHUNKS 32

// ---------------------------------------------------------------------------
__device__ __forceinline__ float wsum64(float v) {
#pragma unroll
  for (int m = 1; m <= 32; m <<= 1) v += __shfl_xor(v, m, 64);
  return v;
}

// 16-lane allreduce sum on the VALU pipe via DPP (no LDS-pipe traffic).
__device__ __forceinline__ float red16(float v) {
  v += __int_as_float(__builtin_amdgcn_update_dpp(0, __float_as_int(v), 0xB1, 0xF, 0xF, true));
  v += __int_as_float(__builtin_amdgcn_update_dpp(0, __float_as_int(v), 0x4E, 0xF, 0xF, true));
  v += __int_as_float(__builtin_amdgcn_update_dpp(0, __float_as_int(v), 0x124, 0xF, 0xF, true));
  v += __int_as_float(__builtin_amdgcn_update_dpp(0, __float_as_int(v), 0x128, 0xF, 0xF, true));
  return v;
}

// ---------------------------------------------------------------------------
// Init + prep fused (7 nodes total). grid = 577 blocks x 64 lanes.
__global__ __launch_bounds__(64) void k_init(
    const float* __restrict__ noise, const float* __restrict__ mu,
    const float* __restrict__ lsig,
    const float* __restrict__ wq, const float* __restrict__ bq,
    const float* __restrict__ wk, const float* __restrict__ bk,
    const float* __restrict__ g_sl, const float* __restrict__ beta_sl,
    float* __restrict__ S_buf, float* __restrict__ qk, float* __restrict__ qb,
    float* __restrict__ acc, float* __restrict__ asum,
    float* __restrict__ M, float* __restrict__ cvec,
    float* __restrict__ uvec, float* __restrict__ s0v)
{
  int bi = blockIdx.x;
  int lane = threadIdx.x;
  if (bi < 512) {
    float sl = mu[lane] + __expf(lsig[lane]) * noise[bi * 64 + lane];
    S_buf[bi * 64 + lane] = sl;
    acc[bi * 64 + lane] = 0.0f;
    if (lane == 0) asum[bi] = 0.0f;

    float s  = wsum64(sl);
    float s2 = wsum64(sl * sl);
    float mean = s * (1.0f / 64.0f);
    float var  = s2 * (1.0f / 64.0f) - mean * mean;
    float rstd = rsqrtf(var + LN_EPS);
    float ln = (sl - mean) * rstd * g_sl[lane] + beta_sl[lane];

    float q = bq[lane];
#pragma unroll
    for (int t = 0; t < 64; ++t) q += __shfl(ln, t, 64) * wq[t * 64 + lane];
    float qkl = 0.0f;
#pragma unroll
    for (int d = 0; d < 64; ++d) qkl += __shfl(q, d, 64) * wk[lane * 64 + d];
    qk[bi * 64 + lane] = qkl * SCALE;
    float qbl = wsum64(q * bk[lane]);
    if (lane == 0) qb[bi] = qbl * SCALE;
  } else if (bi < 576) {
    int t = bi - 512;
    float wqv = wq[t * 64 + lane];
    float m = 0.0f;
#pragma unroll
    for (int d = 0; d < 64; ++d) m += __shfl(wqv, d, 64) * wk[lane * 64 + d];
    M[t * 64 + lane] = m * SCALE;
    float uv = wsum64(wqv * bk[lane]);
    if (lane == 0) uvec[t] = uv * SCALE;
  } else {
    float bqv = bq[lane];
    float cc = 0.0f;
#pragma unroll
    for (int j = 0; j < 64; ++j) cc += __shfl(bqv, j, 64) * wk[lane * 64 + j];
    cvec[lane] = cc * SCALE;
    float ss = wsum64(bq[lane] * bk[lane]);
    if (lane == 0) s0v[0] = ss * SCALE;
  }
}

// ---------------------------------------------------------------------------
// Main streaming pass. grid = (CHUNKS=32, 64), block = 256.
// qk fragments live in LDS (shared by all 4 waves; read once per iteration).
// NO min-waves launch_bounds: round-3 showed capping below live state causes
// a scratch-spill cascade (VGPR 48, WRITE_SIZE 86 MB). Let it land naturally
// (~90-105 VGPR -> 5 waves/SIMD).
__global__ __launch_bounds__(256) void k_main(
    const float* __restrict__ inputs,
    const float* __restrict__ g_in, const float* __restrict__ beta_in,
    const float* __restrict__ qk, const float* __restrict__ qb,
    float* __restrict__ acc, float* __restrict__ asum)
{
  __shared__ float lds_qk[512];
  __shared__ float lds_acc[4][512];
  __shared__ float lds_as[4][8];
  const int b = blockIdx.y;
  const int chunk = blockIdx.x;
  const int tid = threadIdx.x;
  const int lane = tid & 63;
  const int wave = tid >> 6;
  const int p = lane & 15;

  // stage per-batch qk into LDS (2 KB), shared by all waves
  if (tid < 128)
    ((float4*)lds_qk)[tid] = ((const float4*)(qk + b * 512))[tid];

  float4 g4  = ((const float4*)g_in)[p];
  float4 be4 = ((const float4*)beta_in)[p];
  float qbv[8];
#pragma unroll
  for (int i = 0; i < 8; ++i) qbv[i] = qb[b * 8 + i];

  float4 accl[8];
  float asl[8];
#pragma unroll
  for (int i = 0; i < 8; ++i) { accl[i] = make_float4(0.f, 0.f, 0.f, 0.f); asl[i] = 0.f; }

  __syncthreads();  // lds_qk ready

  const float4* in4 = (const float4*)(inputs + (size_t)b * 4096 * 64);
  const float4* qk4 = (const float4*)lds_qk;
  const int rb0 = chunk * 128 + wave * 8;  // this wave's iter-0 base row

  float4 xa = in4[rb0 * 16 + lane];
  float4 xb = in4[(rb0 + 4) * 16 + lane];
  for (int it = 0; it < 4; ++it) {
    float4 na, nb;
    if (it < 3) {
      na = in4[(rb0 + (it + 1) * 32) * 16 + lane];
      nb = in4[(rb0 + (it + 1) * 32 + 4) * 16 + lane];
    }

    // ---- LayerNorm, both groups ----
    float sA  = red16(xa.x + xa.y + xa.z + xa.w);
    float s2A = red16(xa.x * xa.x + xa.y * xa.y + xa.z * xa.z + xa.w * xa.w);
    float meanA = sA * 0.015625f;
    float varA  = s2A * 0.015625f - meanA * meanA;
    float rstdA = rsqrtf(varA + LN_EPS);
    float4 xlnA;
    xlnA.x = (xa.x - meanA) * rstdA * g4.x + be4.x;
    xlnA.y = (xa.y - meanA) * rstdA * g4.y + be4.y;
    xlnA.z = (xa.z - meanA) * rstdA * g4.z + be4.z;
    xlnA.w = (xa.w - meanA) * rstdA * g4.w + be4.w;

    float sB  = red16(xb.x + xb.y + xb.z + xb.w);
    float s2B = red16(xb.x * xb.x + xb.y * xb.y + xb.z * xb.z + xb.w * xb.w);
    float meanB = sB * 0.015625f;
    float varB  = s2B * 0.015625f - meanB * meanB;
    float rstdB = rsqrtf(varB + LN_EPS);
    float4 xlnB;
    xlnB.x = (xb.x - meanB) * rstdB * g4.x + be4.x;
    xlnB.y = (xb.y - meanB) * rstdB * g4.y + be4.y;
    xlnB.z = (xb.z - meanB) * rstdB * g4.z + be4.z;
    xlnB.w = (xb.w - meanB) * rstdB * g4.w + be4.w;

    // ---- dots + exp, qk read ONCE from LDS per slot for both groups ----
    float pvA[8], pvB[8];
    float psA = 0.0f, psB = 0.0f;
#pragma unroll
    for (int i = 0; i < 8; ++i) {
      float4 qv = qk4[i * 16 + p];
      float da = xlnA.x * qv.x + xlnA.y * qv.y + xlnA.z * qv.z + xlnA.w * qv.w;
      float db = xlnB.x * qv.x + xlnB.y * qv.y + xlnB.z * qv.z + xlnB.w * qv.w;
      da = red16(da) + qbv[i];
      db = red16(db) + qbv[i];
      float ea = __expf(da);   // no max-subtraction (|dots| << 88)
      float eb = __expf(db);
      pvA[i] = ea; psA += ea;
      pvB[i] = eb; psB += eb;
    }
    float invA = __builtin_amdgcn_rcpf(psA);
    float invB = __builtin_amdgcn_rcpf(psB);
#pragma unroll
    for (int i = 0; i < 8; ++i) {
      float ppa = pvA[i] * invA + EPS_ATTN;
      float ppb = pvB[i] * invB + EPS_ATTN;
      asl[i] += ppa + ppb;
      accl[i].x += ppa * xlnA.x; accl[i].x += ppb * xlnB.x;
      accl[i].y += ppa * xlnA.y; accl[i].y += ppb * xlnB.y;
      accl[i].z += ppa * xlnA.z; accl[i].z += ppb * xlnB.z;
      accl[i].w += ppa * xlnA.w; accl[i].w += ppb * xlnB.w;
    }
    xa = na;
    xb = nb;
  }

#pragma unroll
  for (int i = 0; i < 8; ++i) {
#pragma unroll
    for (int m = 16; m <= 32; m <<= 1) {
      accl[i].x += __shfl_xor(accl[i].x, m, 64);
      accl[i].y += __shfl_xor(accl[i].y, m, 64);
      accl[i].z += __shfl_xor(accl[i].z, m, 64);
      accl[i].w += __shfl_xor(accl[i].w, m, 64);
      asl[i]    += __shfl_xor(asl[i], m, 64);
    }
  }

  if (lane < 16) {
    float4* dst = (float4*)lds_acc[wave];
#pragma unroll
    for (int i = 0; i < 8; ++i) dst[i * 16 + p] = accl[i];
  }
  if (lane == 0) {
#pragma unroll
    for (int i = 0; i < 8; ++i) lds_as[wave][i] = asl[i];
  }
  __syncthreads();

  for (int f = tid; f < 512; f += 256) {
    float ssum = lds_acc[0][f] + lds_acc[1][f] + lds_acc[2][f] + lds_acc[3][f];
    atomicAdd(&acc[b * 512 + f], ssum);
  }
  if (tid < 8) {
    float ssum = lds_as[0][tid] + lds_as[1][tid] + lds_as[2][tid] + lds_as[3][tid];
    atomicAdd(&asum[b * 8 + tid], ssum);
  }
}

// ---------------------------------------------------------------------------
// Per-slot update, 4 WAVES PER SLOT: 512 blocks x 256 threads.
// Every 64-step accumulation segment is split across the 4 waves (16 e's
// each) with an LDS partial-reduce between segments. 4x issue parallelism
// and 4x weight-load parallelism vs the single-wave version; same math
// modulo reassociation.
__global__ __launch_bounds__(256) void k_update(
    const float* __restrict__ S_in, float* __restrict__ S_out,
    float* __restrict__ acc, float* __restrict__ asum,
    const float* __restrict__ wv, const float* __restrict__ bv,
    const float* __restrict__ w_ih, const float* __restrict__ b_ih,
    const float* __restrict__ w_hh, const float* __restrict__ b_hh,
    const float* __restrict__ w1, const float* __restrict__ b1,
    const float* __restrict__ w2, const float* __restrict__ b2,
    const float* __restrict__ g_ff, const float* __restrict__ beta_ff,
    const float* __restrict__ M, const float* __restrict__ cvec,
    const float* __restrict__ uvec, const float* __restrict__ s0v,
    const float* __restrict__ g_sl, const float* __restrict__ beta_sl,
    float* __restrict__ qk, float* __restrict__ qb, int do_next)
{
  __shared__ float red[6][4][64];
  const int bi   = blockIdx.x;
  const int tid  = threadIdx.x;
  const int lane = tid & 63;
  const int w    = tid >> 6;
  const int e0   = w * 16;

  float asv = asum[bi];
  float v   = acc[bi * 64 + lane] / asv;
  float sp  = S_in[bi * 64 + lane];

  // ---- seg1: updates = v @ wv + bv ----
  float up = 0.0f;
#pragma unroll
  for (int e = 0; e < 16; ++e) {
    float vv = __shfl(v, e0 + e, 64);
    up += vv * wv[(e0 + e) * 64 + lane];
  }
  red[0][w][lane] = up;
  __syncthreads();
  float upd = bv[lane] + red[0][0][lane] + red[0][1][lane]
                       + red[0][2][lane] + red[0][3][lane];

  // ---- seg2: GRU gates ----
  float gxr = 0, gxz = 0, gxn = 0, ghr = 0, ghz = 0, ghn = 0;
#pragma unroll
  for (int e = 0; e < 16; ++e) {
    int ee = e0 + e;
    float uu = __shfl(upd, ee, 64);
    float hh = __shfl(sp, ee, 64);
    const float* wi = w_ih + ee * 192;
    const float* wh = w_hh + ee * 192;
    gxr += uu * wi[lane]; gxz += uu * wi[64 + lane]; gxn += uu * wi[128 + lane];
    ghr += hh * wh[lane]; ghz += hh * wh[64 + lane]; ghn += hh * wh[128 + lane];
  }
  __syncthreads();  // red[0] reads above are done before overwrite
  red[0][w][lane] = gxr; red[1][w][lane] = gxz; red[2][w][lane] = gxn;
  red[3][w][lane] = ghr; red[4][w][lane] = ghz; red[5][w][lane] = ghn;
  __syncthreads();
  gxr = b_ih[lane]       + red[0][0][lane] + red[0][1][lane] + red[0][2][lane] + red[0][3][lane];
  gxz = b_ih[64 + lane]  + red[1][0][lane] + red[1][1][lane] + red[1][2][lane] + red[1][3][lane];
  gxn = b_ih[128 + lane] + red[2][0][lane] + red[2][1][lane] + red[2][2][lane] + red[2][3][lane];
  ghr = b_hh[lane]       + red[3][0][lane] + red[3][1][lane] + red[3][2][lane] + red[3][3][lane];
  ghz = b_hh[64 + lane]  + red[4][0][lane] + red[4][1][lane] + red[4][2][lane] + red[4][3][lane];
  ghn = b_hh[128 + lane] + red[5][0][lane] + red[5][1][lane] + red[5][2][lane] + red[5][3][lane];

  float r  = 1.0f / (1.0f + __expf(-(gxr + ghr)));
  float z  = 1.0f / (1.0f + __expf(-(gxz + ghz)));
  float nw = tanhf(gxn + r * ghn);
  float sn = (1.0f - z) * nw + z * sp;   // identical in all 4 waves

  // ---- LN(sn) (wave-local; sn identical across waves) ----
  float s  = wsum64(sn);
  float s2 = wsum64(sn * sn);
  float mean = s * (1.0f / 64.0f);
  float var  = s2 * (1.0f / 64.0f) - mean * mean;
  float rstd = rsqrtf(var + LN_EPS);
  float ff = (sn - mean) * rstd * g_ff[lane] + beta_ff[lane];

  // ---- seg3: hidden = relu(ff @ w1 + b1) ----
  float h1 = 0.0f, h2 = 0.0f;
#pragma unroll
  for (int e = 0; e < 16; ++e) {
    int ee = e0 + e;
    float f = __shfl(ff, ee, 64);
    h1 += f * w1[ee * 128 + lane];
    h2 += f * w1[ee * 128 + 64 + lane];
  }
  __syncthreads();
  red[0][w][lane] = h1; red[1][w][lane] = h2;
  __syncthreads();
  h1 = fmaxf(b1[lane]      + red[0][0][lane] + red[0][1][lane] + red[0][2][lane] + red[0][3][lane], 0.0f);
  h2 = fmaxf(b1[64 + lane] + red[1][0][lane] + red[1][1][lane] + red[1][2][lane] + red[1][3][lane], 0.0f);

  // ---- seg4: out = sn + hidden @ w2 + b2 (each wave does 16 of 128 t's of
  //      BOTH halves = 32 rows) ----
  float po = 0.0f;
#pragma unroll
  for (int t = 0; t < 16; ++t) {
    int tt = e0 + t;
    po += __shfl(h1, tt, 64) * w2[tt * 64 + lane];
    po += __shfl(h2, tt, 64) * w2[(64 + tt) * 64 + lane];
  }
  __syncthreads();
  red[0][w][lane] = po;
  __syncthreads();
  float o = sn + b2[lane] + red[0][0][lane] + red[0][1][lane]
                          + red[0][2][lane] + red[0][3][lane];
  if (w == 0) S_out[bi * 64 + lane] = o;

  // reset accumulators for the next iteration (reads of acc happened long ago)
  if (do_next && w == 0) {
    acc[bi * 64 + lane] = 0.0f;
    if (lane == 0) asum[bi] = 0.0f;
  }

  if (do_next) {
    // ---- qk for the next iteration: LN(o) @ (wq wk^T scaled) via M ----
    float so  = wsum64(o);
    float so2 = wsum64(o * o);
    float mo  = so * (1.0f / 64.0f);
    float vo  = so2 * (1.0f / 64.0f) - mo * mo;
    float ro  = rsqrtf(vo + LN_EPS);
    float ln  = (o - mo) * ro * g_sl[lane] + beta_sl[lane];

    float pq = 0.0f;
#pragma unroll
    for (int t = 0; t < 16; ++t) {
      int tt = e0 + t;
      pq += __shfl(ln, tt, 64) * M[tt * 64 + lane];
    }
    __syncthreads();
    red[1][w][lane] = pq;
    __syncthreads();
    if (w == 0) {
      qk[bi * 64 + lane] = cvec[lane] + red[1][0][lane] + red[1][1][lane]
                                      + red[1][2][lane] + red[1][3][lane];
      float pb = wsum64(ln * uvec[lane]);
      if (lane == 0) qb[bi] = s0v[0] + pb;
    }
  }
}

// ---------------------------------------------------------------------------
extern "C" void kernel_launch(void* const* d_in, const int* in_sizes, int n_in,
                              void* d_out, int out_size, void* d_ws, size_t ws_size,
                              hipStream_t stream) {
  const float* inputs  = (const float*)d_in[0];
  const float* noise   = (const float*)d_in[1];
  const float* mu      = (const float*)d_in[2];
  const float* lsig    = (const float*)d_in[3];
  const float* wq      = (const float*)d_in[4];
  const float* bq      = (const float*)d_in[5];
  const float* wk      = (const float*)d_in[6];
  const float* bk      = (const float*)d_in[7];
  const float* wv      = (const float*)d_in[8];
  const float* bv      = (const float*)d_in[9];
  const float* w_ih    = (const float*)d_in[10];
  const float* b_ih    = (const float*)d_in[11];
  const float* w_hh    = (const float*)d_in[12];
  const float* b_hh    = (const float*)d_in[13];
  const float* w1      = (const float*)d_in[14];
  const float* b1      = (const float*)d_in[15];
  const float* w2      = (const float*)d_in[16];
  const float* b2      = (const float*)d_in[17];
  const float* g_in    = (const float*)d_in[18];
  const float* beta_in = (const float*)d_in[19];
  const float* g_sl    = (const float*)d_in[20];
  const float* beta_sl = (const float*)d_in[21];
  const float* g_ff    = (const float*)d_in[22];
  const float* beta_ff = (const float*)d_in[23];

  float* S_buf = (float*)d_ws;        // [64*8*64]
  float* qk    = S_buf + 32768;       // [64*8*64]
  float* qb    = qk + 32768;          // [64*8]
  float* acc   = qb + 512;            // [64*8*64]
  float* asum  = acc + 32768;         // [64*8]
  float* M     = asum + 512;          // [64*64]
  float* cvec  = M + 4096;            // [64]
  float* uvec  = cvec + 64;           // [64]
  float* s0v   = uvec + 64;           // [1]
  float* out   = (float*)d_out;

  k_init<<<577, 64, 0, stream>>>(noise, mu, lsig, wq, bq, wk, bk,
                                 g_sl, beta_sl, S_buf, qk, qb, acc, asum,
                                 M, cvec, uvec, s0v);

  for (int t = 0; t < 3; ++t) {
    k_main<<<dim3(CHUNKS, 64), 256, 0, stream>>>(inputs, g_in, beta_in,
                                                 qk, qb, acc, asum);
    float* dst = (t == 2) ? out : S_buf;
    k_update<<<512, 256, 0, stream>>>(S_buf, dst, acc, asum, wv, bv,
                                      w_ih, b_ih, w_hh, b_hh, w1, b1, w2, b2,
                                      g_ff, beta_ff, M, cvec, uvec, s0v,
                                      g_sl, beta_sl, qk, qb, (t == 2) ? 0 : 1);
  }
}